// Round 3
// baseline (637.012 us; speedup 1.0000x reference)
//
#include <hip/hip_runtime.h>
#include <hip/hip_bf16.h>
#include <math.h>

#define H 1024
#define L 128
#define B 256
#define V 32000

typedef __attribute__((ext_vector_type(8))) short bf16x8;
typedef __attribute__((ext_vector_type(4))) float f32x4;

static __device__ __forceinline__ ushort f2bf(float f) {
    unsigned int u = __float_as_uint(f);
    u += 0x7fffu + ((u >> 16) & 1u);   // RNE (finite inputs)
    return (ushort)(u >> 16);
}

// ---------------------------------------------------------------------------
// Kernel 1a: embedding gather + attention logits + softmax.
// One block per batch element. Writes xcat emb-half bf16, h0 bf16,
// attn_weights fp32 (d_out).
// ---------------------------------------------------------------------------
__global__ __launch_bounds__(256) void attn_softmax_kernel(
    const int* __restrict__ input_ids,
    const float* __restrict__ hidden,
    const float* __restrict__ emb_table,
    const float* __restrict__ attn_w,
    const float* __restrict__ attn_b,
    ushort* __restrict__ xcat_b16,         // (B, 2H) bf16
    ushort* __restrict__ h0_b16,           // (B, H) bf16
    float* __restrict__ attn_weights_out)  // (B, L)
{
    __shared__ float s_e[H];
    __shared__ float s_h[H];
    __shared__ float s_part[256];
    __shared__ float s_w[L];
    __shared__ float s_wr[4];

    const int b = blockIdx.x;
    const int tid = threadIdx.x;

    const int id = input_ids[b];
    float4 ev = ((const float4*)(emb_table + (size_t)id * H))[tid];
    float4 hv = ((const float4*)(hidden + (size_t)b * H))[tid];
    ((float4*)s_e)[tid] = ev;
    ((float4*)s_h)[tid] = hv;

    {
        uint2 p;
        p.x = (unsigned)f2bf(ev.x) | ((unsigned)f2bf(ev.y) << 16);
        p.y = (unsigned)f2bf(ev.z) | ((unsigned)f2bf(ev.w) << 16);
        *(uint2*)(xcat_b16 + (size_t)b * 2 * H + tid * 4) = p;
        uint2 q;
        q.x = (unsigned)f2bf(hv.x) | ((unsigned)f2bf(hv.y) << 16);
        q.y = (unsigned)f2bf(hv.z) | ((unsigned)f2bf(hv.w) << 16);
        *(uint2*)(h0_b16 + (size_t)b * H + tid * 4) = q;
    }
    __syncthreads();

    const int l = tid & 127;
    const int half = tid >> 7;
    const float4* w4 = (const float4*)(attn_w + (size_t)l * (2 * H) + half * H);
    const float4* s4 = (const float4*)(half ? s_h : s_e);
    float acc = 0.f;
#pragma unroll 4
    for (int k = 0; k < H / 4; ++k) {
        float4 w = w4[k];
        float4 s = s4[k];
        acc += w.x * s.x + w.y * s.y + w.z * s.z + w.w * s.w;
    }
    s_part[tid] = acc;
    __syncthreads();
    if (tid < L) s_w[tid] = s_part[tid] + s_part[tid + 128] + attn_b[tid];
    __syncthreads();

    const int wid = tid >> 6;
    float v = (tid < L) ? s_w[tid] : -INFINITY;
    for (int off = 32; off; off >>= 1) v = fmaxf(v, __shfl_xor(v, off));
    if ((tid & 63) == 0) s_wr[wid] = v;
    __syncthreads();
    const float m = fmaxf(s_wr[0], s_wr[1]);

    float e = 0.f;
    if (tid < L) e = __expf(s_w[tid] - m);
    float sv = e;
    for (int off = 32; off; off >>= 1) sv += __shfl_xor(sv, off);
    __syncthreads();
    if ((tid & 63) == 0) s_wr[wid] = sv;
    __syncthreads();
    const float inv = 1.f / (s_wr[0] + s_wr[1]);
    if (tid < L) attn_weights_out[(size_t)b * L + tid] = e * inv;
}

// ---------------------------------------------------------------------------
// Kernel 1b: weighted sum over encoder outputs.
// Block (c, b): 128 columns of H for batch b.  grid (8, B) = 2048 blocks.
// ---------------------------------------------------------------------------
__global__ __launch_bounds__(256) void attn_apply_kernel(
    const float* __restrict__ enc,              // (B, L, H)
    const float* __restrict__ attn_weights,     // (B, L)
    ushort* __restrict__ xcat_b16)              // (B, 2H)
{
    __shared__ float s_w[L];
    __shared__ float4 s_red[256];

    const int c = blockIdx.x;     // 0..7 column chunk
    const int b = blockIdx.y;
    const int tid = threadIdx.x;
    const int lg = tid >> 5;      // 0..7 (l-group)
    const int hc = tid & 31;      // 0..31 (float4 column)

    if (tid < L) s_w[tid] = attn_weights[(size_t)b * L + tid];
    __syncthreads();

    const float4* enc4 = (const float4*)enc;
    float4 a = {0.f, 0.f, 0.f, 0.f};
#pragma unroll
    for (int it = 0; it < 16; ++it) {
        const int ll = it * 8 + lg;
        const float w = s_w[ll];
        float4 e2 = enc4[((size_t)b * L + ll) * (H / 4) + c * 32 + hc];
        a.x += w * e2.x; a.y += w * e2.y; a.z += w * e2.z; a.w += w * e2.w;
    }
    s_red[tid] = a;
    __syncthreads();
    if (tid < 32) {
        float4 t = s_red[tid];
#pragma unroll
        for (int j = 1; j < 8; ++j) {
            float4 o = s_red[j * 32 + tid];
            t.x += o.x; t.y += o.y; t.z += o.z; t.w += o.w;
        }
        uint2 p;
        p.x = (unsigned)f2bf(t.x) | ((unsigned)f2bf(t.y) << 16);
        p.y = (unsigned)f2bf(t.z) | ((unsigned)f2bf(t.w) << 16);
        *(uint2*)(xcat_b16 + (size_t)b * 2 * H + H + c * 128 + tid * 4) = p;
    }
}

// ---------------------------------------------------------------------------
// bf16 MFMA GEMM with register-prefetch pipeline.
// C = A(B rows, K bf16) @ W(N, K fp32->bf16).T + bias
// Grid: (N/NT, B/MT).  BLK threads.  Waves split M.
// MODE 0: write fp32   MODE 1: relu + write bf16
// MODE 2: rowsum[row] += sum_col exp(logit) (atomic), no C write
// MODE 3: write fp32 logp = logit - log(rowsum[row])
// ---------------------------------------------------------------------------
template<int BLK, int MT, int NT, int K, int MODE>
__global__ __launch_bounds__(BLK) void mfma_gemm(
    const ushort* __restrict__ A,
    const float* __restrict__ W,
    const float* __restrict__ bias,
    float* __restrict__ outf,
    ushort* __restrict__ outb,
    float* __restrict__ rowsum,
    int N)
{
    constexpr int WAVES = BLK / 64;
    constexpr int RPW = MT / WAVES;       // rows per wave
    constexpr int NI = RPW / 16;          // 16-row groups per wave
    constexpr int NN = NT / 16;           // 16-col groups
    constexpr int PA = (MT * 8) / BLK;    // A staging passes (16B/thread)
    constexpr int PW = (NT * 8 + BLK - 1) / BLK;
    constexpr int LDA = 72;               // padded row in ushorts

    __shared__ ushort sA[MT * LDA];
    __shared__ ushort sW[NT * LDA];
    __shared__ float sLse[MT];

    const int tid = threadIdx.x;
    const int bn = blockIdx.x * NT;
    const int bm = blockIdx.y * MT;
    const int wv = tid >> 6;
    const int lane = tid & 63;
    const int g = lane >> 4;
    const int ln = lane & 15;
    const int trow = tid >> 3;
    const int tcol = tid & 7;

    if (MODE == 3 && tid < MT) sLse[tid] = __logf(rowsum[bm + tid]);

    uint4 aReg[PA];
    float4 wReg[PW][2];

    auto prefetch = [&](int k0) {
#pragma unroll
        for (int p = 0; p < PA; ++p) {
            const int r = p * (BLK / 8) + trow;
            aReg[p] = *(const uint4*)(A + (size_t)(bm + r) * K + k0 + tcol * 8);
        }
#pragma unroll
        for (int p = 0; p < PW; ++p) {
            const int r = p * (BLK / 8) + trow;
            if (NT * 8 >= BLK || r < NT) {
                const float* wp = W + (size_t)(bn + r) * K + k0 + tcol * 8;
                wReg[p][0] = *(const float4*)wp;
                wReg[p][1] = *(const float4*)(wp + 4);
            }
        }
    };
    auto stage = [&]() {
#pragma unroll
        for (int p = 0; p < PA; ++p) {
            const int r = p * (BLK / 8) + trow;
            *(uint4*)(sA + r * LDA + tcol * 8) = aReg[p];
        }
#pragma unroll
        for (int p = 0; p < PW; ++p) {
            const int r = p * (BLK / 8) + trow;
            if (NT * 8 >= BLK || r < NT) {
                ushort t[8];
                t[0] = f2bf(wReg[p][0].x); t[1] = f2bf(wReg[p][0].y);
                t[2] = f2bf(wReg[p][0].z); t[3] = f2bf(wReg[p][0].w);
                t[4] = f2bf(wReg[p][1].x); t[5] = f2bf(wReg[p][1].y);
                t[6] = f2bf(wReg[p][1].z); t[7] = f2bf(wReg[p][1].w);
                *(uint4*)(sW + r * LDA + tcol * 8) = *(const uint4*)t;
            }
        }
    };

    f32x4 acc[NI][NN];
#pragma unroll
    for (int i = 0; i < NI; ++i)
#pragma unroll
        for (int n = 0; n < NN; ++n)
            acc[i][n] = (f32x4){0.f, 0.f, 0.f, 0.f};

    prefetch(0);
    for (int k0 = 0; k0 < K; k0 += 64) {
        __syncthreads();   // LDS free from previous iteration's reads
        stage();
        __syncthreads();
        if (k0 + 64 < K) prefetch(k0 + 64);   // latency overlaps MFMA phase
#pragma unroll
        for (int s = 0; s < 2; ++s) {
            bf16x8 af[NI], bfr[NN];
#pragma unroll
            for (int i = 0; i < NI; ++i)
                af[i] = *(const bf16x8*)(sA + (wv * RPW + 16 * i + ln) * LDA + s * 32 + g * 8);
#pragma unroll
            for (int n = 0; n < NN; ++n)
                bfr[n] = *(const bf16x8*)(sW + (16 * n + ln) * LDA + s * 32 + g * 8);
#pragma unroll
            for (int i = 0; i < NI; ++i)
#pragma unroll
                for (int n = 0; n < NN; ++n)
                    acc[i][n] = __builtin_amdgcn_mfma_f32_16x16x32_bf16(af[i], bfr[n], acc[i][n], 0, 0, 0);
        }
    }

    float bb[NN];
#pragma unroll
    for (int n = 0; n < NN; ++n) bb[n] = bias[bn + 16 * n + ln];

    if (MODE == 0) {
#pragma unroll
        for (int i = 0; i < NI; ++i)
#pragma unroll
            for (int n = 0; n < NN; ++n)
#pragma unroll
                for (int r = 0; r < 4; ++r)
                    outf[(size_t)(bm + wv * RPW + 16 * i + 4 * g + r) * N + bn + 16 * n + ln] =
                        acc[i][n][r] + bb[n];
    } else if (MODE == 1) {
#pragma unroll
        for (int i = 0; i < NI; ++i)
#pragma unroll
            for (int n = 0; n < NN; ++n)
#pragma unroll
                for (int r = 0; r < 4; ++r) {
                    float vv = fmaxf(acc[i][n][r] + bb[n], 0.f);
                    outb[(size_t)(bm + wv * RPW + 16 * i + 4 * g + r) * N + bn + 16 * n + ln] = f2bf(vv);
                }
    } else if (MODE == 2) {
#pragma unroll
        for (int i = 0; i < NI; ++i) {
            float e[4];
#pragma unroll
            for (int r = 0; r < 4; ++r) {
                e[r] = 0.f;
#pragma unroll
                for (int n = 0; n < NN; ++n)
                    e[r] += __expf(acc[i][n][r] + bb[n]);
            }
#pragma unroll
            for (int msk = 1; msk < 16; msk <<= 1)
#pragma unroll
                for (int r = 0; r < 4; ++r)
                    e[r] += __shfl_xor(e[r], msk);
            if (ln < 4)
                atomicAdd(&rowsum[bm + wv * RPW + 16 * i + 4 * g + ln], e[ln]);
        }
    } else {  // MODE 3
#pragma unroll
        for (int i = 0; i < NI; ++i)
#pragma unroll
            for (int n = 0; n < NN; ++n)
#pragma unroll
                for (int r = 0; r < 4; ++r) {
                    const int lrow = wv * RPW + 16 * i + 4 * g + r;
                    outf[(size_t)(bm + lrow) * N + bn + 16 * n + ln] =
                        acc[i][n][r] + bb[n] - sLse[lrow];
                }
    }
}

// ---------------------------------------------------------------------------
// GRU gates; also emits h_new in bf16 and zeroes rowsum (block 0).
// ---------------------------------------------------------------------------
__global__ __launch_bounds__(256) void gru_kernel(
    const float* __restrict__ gx,
    const float* __restrict__ gh,
    const float* __restrict__ h0,
    float* __restrict__ h_new,
    ushort* __restrict__ hn_b16,
    float* __restrict__ rowsum)
{
    if (blockIdx.x == 0) rowsum[threadIdx.x] = 0.f;
    const int idx = blockIdx.x * 256 + threadIdx.x;
    const int b = idx >> 10;
    const int j = idx & (H - 1);
    const size_t base = (size_t)b * 3 * H;
    const float xr = gx[base + j];
    const float xz = gx[base + H + j];
    const float xn = gx[base + 2 * H + j];
    const float hr = gh[base + j];
    const float hz = gh[base + H + j];
    const float hn = gh[base + 2 * H + j];
    const float r = 1.f / (1.f + __expf(-(xr + hr)));
    const float z = 1.f / (1.f + __expf(-(xz + hz)));
    const float n = tanhf(xn + r * hn);
    const float out = (1.f - z) * n + z * h0[idx];
    h_new[idx] = out;
    hn_b16[idx] = f2bf(out);
}

// ---------------------------------------------------------------------------
extern "C" void kernel_launch(void* const* d_in, const int* in_sizes, int n_in,
                              void* d_out, int out_size, void* d_ws, size_t ws_size,
                              hipStream_t stream) {
    const int*   input_ids = (const int*)d_in[0];
    const float* hidden    = (const float*)d_in[1];
    const float* enc       = (const float*)d_in[2];
    const float* emb_table = (const float*)d_in[3];
    const float* attn_w    = (const float*)d_in[4];
    const float* attn_b    = (const float*)d_in[5];
    const float* comb_w    = (const float*)d_in[6];
    const float* comb_b    = (const float*)d_in[7];
    const float* w_ih      = (const float*)d_in[8];
    const float* b_ih      = (const float*)d_in[9];
    const float* w_hh      = (const float*)d_in[10];
    const float* b_hh      = (const float*)d_in[11];
    const float* out_w     = (const float*)d_in[12];
    const float* out_b     = (const float*)d_in[13];

    float* out = (float*)d_out;
    float* logp         = out;                    // (B, V)
    float* h_new        = out + (size_t)B * V;    // (B, H)
    float* attn_weights = h_new + (size_t)B * H;  // (B, L)

    ushort* xcat_b16 = (ushort*)d_ws;                          // B*2H
    ushort* h0_b16   = xcat_b16 + (size_t)B * 2 * H;           // B*H
    ushort* x_b16    = h0_b16 + (size_t)B * H;                 // B*H
    ushort* hn_b16   = x_b16 + (size_t)B * H;                  // B*H
    float*  gx       = (float*)(hn_b16 + (size_t)B * H);       // B*3H
    float*  gh       = gx + (size_t)B * 3 * H;                 // B*3H
    float*  rowsum   = gh + (size_t)B * 3 * H;                 // B

    // 1a. logits + softmax (+ bf16 casts of emb and h0)
    attn_softmax_kernel<<<dim3(B), dim3(256), 0, stream>>>(
        input_ids, hidden, emb_table, attn_w, attn_b,
        xcat_b16, h0_b16, attn_weights);

    // 1b. weighted sum over enc -> xcat attn half   (2048 blocks)
    attn_apply_kernel<<<dim3(8, B), dim3(256), 0, stream>>>(
        enc, attn_weights, xcat_b16);

    // 2. x = relu(xcat @ comb_w.T + comb_b) -> bf16   (grid 64x4)
    mfma_gemm<256, 64, 16, 2 * H, 1><<<dim3(H / 16, B / 64), dim3(256), 0, stream>>>(
        xcat_b16, comb_w, comb_b, nullptr, x_b16, nullptr, H);

    // 3. gx = x @ w_ih.T + b_ih   (grid 96x4)
    mfma_gemm<256, 64, 32, H, 0><<<dim3(3 * H / 32, B / 64), dim3(256), 0, stream>>>(
        x_b16, w_ih, b_ih, gx, nullptr, nullptr, 3 * H);

    // 4. gh = h0 @ w_hh.T + b_hh   (grid 96x4)
    mfma_gemm<256, 64, 32, H, 0><<<dim3(3 * H / 32, B / 64), dim3(256), 0, stream>>>(
        h0_b16, w_hh, b_hh, gh, nullptr, nullptr, 3 * H);

    // 5. GRU gates -> h_new (fp32 + bf16), zero rowsum
    gru_kernel<<<dim3(B * H / 256), dim3(256), 0, stream>>>(
        gx, gh, hidden, h_new, hn_b16, rowsum);

    // 6. V-GEMM pass 1: rowsum[b] = sum_v exp(logit)   (grid 500)
    mfma_gemm<512, 256, 64, H, 2><<<dim3(V / 64, 1), dim3(512), 0, stream>>>(
        hn_b16, out_w, out_b, nullptr, nullptr, rowsum, V);

    // 7. V-GEMM pass 2: logp = logit - log(rowsum)   (grid 500)
    mfma_gemm<512, 256, 64, H, 3><<<dim3(V / 64, 1), dim3(512), 0, stream>>>(
        hn_b16, out_w, out_b, logp, nullptr, rowsum, V);
}

// Round 4
// 629.917 us; speedup vs baseline: 1.0113x; 1.0113x over previous
//
#include <hip/hip_runtime.h>
#include <hip/hip_bf16.h>
#include <math.h>

#define H 1024
#define L 128
#define B 256
#define V 32000
#define PPAD 1024   // padded partial-row stride (1000 blocks -> 1024)

typedef __attribute__((ext_vector_type(8))) short bf16x8;
typedef __attribute__((ext_vector_type(4))) float f32x4;

static __device__ __forceinline__ ushort f2bf(float f) {
    unsigned int u = __float_as_uint(f);
    u += 0x7fffu + ((u >> 16) & 1u);   // RNE (finite inputs)
    return (ushort)(u >> 16);
}

// ---------------------------------------------------------------------------
// Kernel 1a: embedding gather + attention logits + softmax.
// One block per batch element. Also zeroes the pad tail of the partial matrix.
// ---------------------------------------------------------------------------
__global__ __launch_bounds__(256) void attn_softmax_kernel(
    const int* __restrict__ input_ids,
    const float* __restrict__ hidden,
    const float* __restrict__ emb_table,
    const float* __restrict__ attn_w,
    const float* __restrict__ attn_b,
    ushort* __restrict__ xcat_b16,         // (B, 2H) bf16
    ushort* __restrict__ h0_b16,           // (B, H) bf16
    float* __restrict__ attn_weights_out,  // (B, L)
    float* __restrict__ partial)           // (B, PPAD) — zero pad cols 1000..1023
{
    __shared__ float s_e[H];
    __shared__ float s_h[H];
    __shared__ float s_part[256];
    __shared__ float s_w[L];
    __shared__ float s_wr[4];

    const int b = blockIdx.x;
    const int tid = threadIdx.x;

    if (tid < PPAD - 1000) partial[(size_t)b * PPAD + 1000 + tid] = 0.f;

    const int id = input_ids[b];
    float4 ev = ((const float4*)(emb_table + (size_t)id * H))[tid];
    float4 hv = ((const float4*)(hidden + (size_t)b * H))[tid];
    ((float4*)s_e)[tid] = ev;
    ((float4*)s_h)[tid] = hv;

    {
        uint2 p;
        p.x = (unsigned)f2bf(ev.x) | ((unsigned)f2bf(ev.y) << 16);
        p.y = (unsigned)f2bf(ev.z) | ((unsigned)f2bf(ev.w) << 16);
        *(uint2*)(xcat_b16 + (size_t)b * 2 * H + tid * 4) = p;
        uint2 q;
        q.x = (unsigned)f2bf(hv.x) | ((unsigned)f2bf(hv.y) << 16);
        q.y = (unsigned)f2bf(hv.z) | ((unsigned)f2bf(hv.w) << 16);
        *(uint2*)(h0_b16 + (size_t)b * H + tid * 4) = q;
    }
    __syncthreads();

    const int l = tid & 127;
    const int half = tid >> 7;
    const float4* w4 = (const float4*)(attn_w + (size_t)l * (2 * H) + half * H);
    const float4* s4 = (const float4*)(half ? s_h : s_e);
    float acc = 0.f;
#pragma unroll 4
    for (int k = 0; k < H / 4; ++k) {
        float4 w = w4[k];
        float4 s = s4[k];
        acc += w.x * s.x + w.y * s.y + w.z * s.z + w.w * s.w;
    }
    s_part[tid] = acc;
    __syncthreads();
    if (tid < L) s_w[tid] = s_part[tid] + s_part[tid + 128] + attn_b[tid];
    __syncthreads();

    const int wid = tid >> 6;
    float v = (tid < L) ? s_w[tid] : -INFINITY;
    for (int off = 32; off; off >>= 1) v = fmaxf(v, __shfl_xor(v, off));
    if ((tid & 63) == 0) s_wr[wid] = v;
    __syncthreads();
    const float m = fmaxf(s_wr[0], s_wr[1]);

    float e = 0.f;
    if (tid < L) e = __expf(s_w[tid] - m);
    float sv = e;
    for (int off = 32; off; off >>= 1) sv += __shfl_xor(sv, off);
    __syncthreads();
    if ((tid & 63) == 0) s_wr[wid] = sv;
    __syncthreads();
    const float inv = 1.f / (s_wr[0] + s_wr[1]);
    if (tid < L) attn_weights_out[(size_t)b * L + tid] = e * inv;
}

// ---------------------------------------------------------------------------
// Kernel 1b: weighted sum over encoder outputs.  grid (8, B) = 2048 blocks.
// ---------------------------------------------------------------------------
__global__ __launch_bounds__(256) void attn_apply_kernel(
    const float* __restrict__ enc,              // (B, L, H)
    const float* __restrict__ attn_weights,     // (B, L)
    ushort* __restrict__ xcat_b16)              // (B, 2H)
{
    __shared__ float s_w[L];
    __shared__ float4 s_red[256];

    const int c = blockIdx.x;
    const int b = blockIdx.y;
    const int tid = threadIdx.x;
    const int lg = tid >> 5;
    const int hc = tid & 31;

    if (tid < L) s_w[tid] = attn_weights[(size_t)b * L + tid];
    __syncthreads();

    const float4* enc4 = (const float4*)enc;
    float4 a = {0.f, 0.f, 0.f, 0.f};
#pragma unroll
    for (int it = 0; it < 16; ++it) {
        const int ll = it * 8 + lg;
        const float w = s_w[ll];
        float4 e2 = enc4[((size_t)b * L + ll) * (H / 4) + c * 32 + hc];
        a.x += w * e2.x; a.y += w * e2.y; a.z += w * e2.z; a.w += w * e2.w;
    }
    s_red[tid] = a;
    __syncthreads();
    if (tid < 32) {
        float4 t = s_red[tid];
#pragma unroll
        for (int j = 1; j < 8; ++j) {
            float4 o = s_red[j * 32 + tid];
            t.x += o.x; t.y += o.y; t.z += o.z; t.w += o.w;
        }
        uint2 p;
        p.x = (unsigned)f2bf(t.x) | ((unsigned)f2bf(t.y) << 16);
        p.y = (unsigned)f2bf(t.z) | ((unsigned)f2bf(t.w) << 16);
        *(uint2*)(xcat_b16 + (size_t)b * 2 * H + H + c * 128 + tid * 4) = p;
    }
}

// ---------------------------------------------------------------------------
// bf16 MFMA GEMM with register-prefetch pipeline and blockIdx.z operand select.
// C = A @ W.T + bias.   Grid: (N/NT, M/MT, z).
// MODE 0: write fp32
// MODE 1: relu + write bf16
// MODE 4: write fp32 logits + per-block partial sum_cols exp(logit) (no atomics)
// ---------------------------------------------------------------------------
template<int BLK, int MT, int NT, int K, int MODE>
__global__ __launch_bounds__(BLK) void mfma_gemm(
    const ushort* __restrict__ A0, const ushort* __restrict__ A1,
    const float* __restrict__ W0, const float* __restrict__ W1,
    const float* __restrict__ bias0, const float* __restrict__ bias1,
    float* __restrict__ outf0, float* __restrict__ outf1,
    ushort* __restrict__ outb,
    float* __restrict__ partial,
    int N)
{
    constexpr int WAVES = BLK / 64;
    constexpr int RPW = MT / WAVES;       // rows per wave
    constexpr int NI = RPW / 16;
    constexpr int NN = NT / 16;
    constexpr int PA = (MT * 8) / BLK;    // A staging passes (16B/thread)
    constexpr int PW = (NT * 8) / BLK;    // W staging passes (exact by config)
    constexpr int LDA = 72;

    __shared__ ushort sA[MT * LDA];
    __shared__ ushort sW[NT * LDA];

    const int z = blockIdx.z;
    const ushort* __restrict__ A   = z ? A1 : A0;
    const float* __restrict__ W    = z ? W1 : W0;
    const float* __restrict__ bias = z ? bias1 : bias0;
    float* __restrict__ outf       = z ? outf1 : outf0;

    const int tid = threadIdx.x;
    const int nb = blockIdx.x;
    const int bn = nb * NT;
    const int bm = blockIdx.y * MT;
    const int wv = tid >> 6;
    const int lane = tid & 63;
    const int g = lane >> 4;
    const int ln = lane & 15;
    const int trow = tid >> 3;
    const int tcol = tid & 7;

    uint4 aReg[PA];
    float4 wReg[PW][2];

    auto prefetch = [&](int k0) {
#pragma unroll
        for (int p = 0; p < PA; ++p) {
            const int r = p * (BLK / 8) + trow;
            aReg[p] = *(const uint4*)(A + (size_t)(bm + r) * K + k0 + tcol * 8);
        }
#pragma unroll
        for (int p = 0; p < PW; ++p) {
            const int r = p * (BLK / 8) + trow;
            const float* wp = W + (size_t)(bn + r) * K + k0 + tcol * 8;
            wReg[p][0] = *(const float4*)wp;
            wReg[p][1] = *(const float4*)(wp + 4);
        }
    };
    auto stage = [&]() {
#pragma unroll
        for (int p = 0; p < PA; ++p) {
            const int r = p * (BLK / 8) + trow;
            *(uint4*)(sA + r * LDA + tcol * 8) = aReg[p];
        }
#pragma unroll
        for (int p = 0; p < PW; ++p) {
            const int r = p * (BLK / 8) + trow;
            ushort t[8];
            t[0] = f2bf(wReg[p][0].x); t[1] = f2bf(wReg[p][0].y);
            t[2] = f2bf(wReg[p][0].z); t[3] = f2bf(wReg[p][0].w);
            t[4] = f2bf(wReg[p][1].x); t[5] = f2bf(wReg[p][1].y);
            t[6] = f2bf(wReg[p][1].z); t[7] = f2bf(wReg[p][1].w);
            *(uint4*)(sW + r * LDA + tcol * 8) = *(const uint4*)t;
        }
    };

    f32x4 acc[NI][NN];
#pragma unroll
    for (int i = 0; i < NI; ++i)
#pragma unroll
        for (int n = 0; n < NN; ++n)
            acc[i][n] = (f32x4){0.f, 0.f, 0.f, 0.f};

    prefetch(0);
    for (int k0 = 0; k0 < K; k0 += 64) {
        __syncthreads();
        stage();
        __syncthreads();
        if (k0 + 64 < K) prefetch(k0 + 64);
#pragma unroll
        for (int s = 0; s < 2; ++s) {
            bf16x8 af[NI], bfr[NN];
#pragma unroll
            for (int i = 0; i < NI; ++i)
                af[i] = *(const bf16x8*)(sA + (wv * RPW + 16 * i + ln) * LDA + s * 32 + g * 8);
#pragma unroll
            for (int n = 0; n < NN; ++n)
                bfr[n] = *(const bf16x8*)(sW + (16 * n + ln) * LDA + s * 32 + g * 8);
#pragma unroll
            for (int i = 0; i < NI; ++i)
#pragma unroll
                for (int n = 0; n < NN; ++n)
                    acc[i][n] = __builtin_amdgcn_mfma_f32_16x16x32_bf16(af[i], bfr[n], acc[i][n], 0, 0, 0);
        }
    }

    float bb[NN];
#pragma unroll
    for (int n = 0; n < NN; ++n) bb[n] = bias[bn + 16 * n + ln];

    if (MODE == 0) {
#pragma unroll
        for (int i = 0; i < NI; ++i)
#pragma unroll
            for (int n = 0; n < NN; ++n)
#pragma unroll
                for (int r = 0; r < 4; ++r)
                    outf[(size_t)(bm + wv * RPW + 16 * i + 4 * g + r) * N + bn + 16 * n + ln] =
                        acc[i][n][r] + bb[n];
    } else if (MODE == 1) {
#pragma unroll
        for (int i = 0; i < NI; ++i)
#pragma unroll
            for (int n = 0; n < NN; ++n)
#pragma unroll
                for (int r = 0; r < 4; ++r) {
                    float vv = fmaxf(acc[i][n][r] + bb[n], 0.f);
                    outb[(size_t)(bm + wv * RPW + 16 * i + 4 * g + r) * N + bn + 16 * n + ln] = f2bf(vv);
                }
    } else {  // MODE 4: logits + per-block partial exp sums
#pragma unroll
        for (int i = 0; i < NI; ++i) {
            float es[4];
#pragma unroll
            for (int r = 0; r < 4; ++r) es[r] = 0.f;
#pragma unroll
            for (int n = 0; n < NN; ++n)
#pragma unroll
                for (int r = 0; r < 4; ++r) {
                    const float lv = acc[i][n][r] + bb[n];
                    outf[(size_t)(bm + wv * RPW + 16 * i + 4 * g + r) * N + bn + 16 * n + ln] = lv;
                    es[r] += __expf(lv);
                }
#pragma unroll
            for (int msk = 1; msk < 16; msk <<= 1)
#pragma unroll
                for (int r = 0; r < 4; ++r)
                    es[r] += __shfl_xor(es[r], msk);
            if (ln < 4)   // one lane per (g,r) row writes; use ln as r-selector
                partial[(size_t)(bm + wv * RPW + 16 * i + 4 * g + ln) * PPAD + nb] = es[ln];
        }
    }
}

// ---------------------------------------------------------------------------
// GRU gates; emits h_new fp32 (d_out) + bf16 (ws).
// ---------------------------------------------------------------------------
__global__ __launch_bounds__(256) void gru_kernel(
    const float* __restrict__ gx,
    const float* __restrict__ gh,
    const float* __restrict__ h0,
    float* __restrict__ h_new,
    ushort* __restrict__ hn_b16)
{
    const int idx = blockIdx.x * 256 + threadIdx.x;
    const int b = idx >> 10;
    const int j = idx & (H - 1);
    const size_t base = (size_t)b * 3 * H;
    const float xr = gx[base + j];
    const float xz = gx[base + H + j];
    const float xn = gx[base + 2 * H + j];
    const float hr = gh[base + j];
    const float hz = gh[base + H + j];
    const float hn = gh[base + 2 * H + j];
    const float r = 1.f / (1.f + __expf(-(xr + hr)));
    const float z = 1.f / (1.f + __expf(-(xz + hz)));
    const float n = tanhf(xn + r * hn);
    const float out = (1.f - z) * n + z * h0[idx];
    h_new[idx] = out;
    hn_b16[idx] = f2bf(out);
}

// ---------------------------------------------------------------------------
// lse: reduce partial (B, PPAD) -> lse[b] = log(sum).  256 blocks.
// ---------------------------------------------------------------------------
__global__ __launch_bounds__(256) void lse_kernel(
    const float* __restrict__ partial,
    float* __restrict__ lse)
{
    __shared__ float s_r[4];
    const int b = blockIdx.x;
    const int tid = threadIdx.x;
    const float* row = partial + (size_t)b * PPAD;
    float s = row[tid] + row[tid + 256] + row[tid + 512] + row[tid + 768];
    for (int off = 32; off; off >>= 1) s += __shfl_xor(s, off);
    if ((tid & 63) == 0) s_r[tid >> 6] = s;
    __syncthreads();
    if (tid == 0) lse[b] = __logf(s_r[0] + s_r[1] + s_r[2] + s_r[3]);
}

// ---------------------------------------------------------------------------
// subtract: logp[b, :] -= lse[b]  (vectorized in place).  2000 blocks.
// ---------------------------------------------------------------------------
__global__ __launch_bounds__(256) void sub_kernel(
    float4* __restrict__ logp4,
    const float* __restrict__ lse)
{
    const int i = blockIdx.x * 256 + threadIdx.x;
#pragma unroll
    for (int k = 0; k < 4; ++k) {
        const int idx = i + k * 512000;          // B*V/4 = 2,048,000 exact
        const int row = idx / (V / 4);
        const float l = lse[row];
        float4 v = logp4[idx];
        v.x -= l; v.y -= l; v.z -= l; v.w -= l;
        logp4[idx] = v;
    }
}

// ---------------------------------------------------------------------------
extern "C" void kernel_launch(void* const* d_in, const int* in_sizes, int n_in,
                              void* d_out, int out_size, void* d_ws, size_t ws_size,
                              hipStream_t stream) {
    const int*   input_ids = (const int*)d_in[0];
    const float* hidden    = (const float*)d_in[1];
    const float* enc       = (const float*)d_in[2];
    const float* emb_table = (const float*)d_in[3];
    const float* attn_w    = (const float*)d_in[4];
    const float* attn_b    = (const float*)d_in[5];
    const float* comb_w    = (const float*)d_in[6];
    const float* comb_b    = (const float*)d_in[7];
    const float* w_ih      = (const float*)d_in[8];
    const float* b_ih      = (const float*)d_in[9];
    const float* w_hh      = (const float*)d_in[10];
    const float* b_hh      = (const float*)d_in[11];
    const float* out_w     = (const float*)d_in[12];
    const float* out_b     = (const float*)d_in[13];

    float* out = (float*)d_out;
    float* logp         = out;                    // (B, V)
    float* h_new        = out + (size_t)B * V;    // (B, H)
    float* attn_weights = h_new + (size_t)B * H;  // (B, L)

    ushort* xcat_b16 = (ushort*)d_ws;                          // B*2H bf16
    ushort* h0_b16   = xcat_b16 + (size_t)B * 2 * H;           // B*H
    ushort* x_b16    = h0_b16 + (size_t)B * H;                 // B*H
    ushort* hn_b16   = x_b16 + (size_t)B * H;                  // B*H
    float*  gx       = (float*)(hn_b16 + (size_t)B * H);       // B*3H fp32
    float*  gh       = gx + (size_t)B * 3 * H;                 // B*3H
    float*  partial  = gh + (size_t)B * 3 * H;                 // B*PPAD
    float*  lse      = partial + (size_t)B * PPAD;             // B

    // 1a. logits + softmax (+ bf16 casts, + zero partial pad)
    attn_softmax_kernel<<<dim3(B), dim3(256), 0, stream>>>(
        input_ids, hidden, emb_table, attn_w, attn_b,
        xcat_b16, h0_b16, attn_weights, partial);

    // 1b. weighted sum over enc -> xcat attn half   (2048 blocks)
    attn_apply_kernel<<<dim3(8, B), dim3(256), 0, stream>>>(
        enc, attn_weights, xcat_b16);

    // 2. x = relu(xcat @ comb_w.T + comb_b) -> bf16   (512 blocks)
    mfma_gemm<128, 32, 16, 2 * H, 1><<<dim3(H / 16, B / 32, 1), dim3(128), 0, stream>>>(
        xcat_b16, xcat_b16, comb_w, comb_w, comb_b, comb_b,
        nullptr, nullptr, x_b16, nullptr, H);

    // 3+4. gx = x @ w_ih.T + b_ih ; gh = h0 @ w_hh.T + b_hh  (fused, 1536 blocks)
    mfma_gemm<128, 32, 32, H, 0><<<dim3(3 * H / 32, B / 32, 2), dim3(128), 0, stream>>>(
        x_b16, h0_b16, w_ih, w_hh, b_ih, b_hh,
        gx, gh, nullptr, nullptr, 3 * H);

    // 5. GRU gates -> h_new (fp32 + bf16)
    gru_kernel<<<dim3(B * H / 256), dim3(256), 0, stream>>>(
        gx, gh, hidden, h_new, hn_b16);

    // 6. V-GEMM single pass: logits -> logp, partial exp-sums -> partial (2000 blocks)
    mfma_gemm<256, 128, 32, H, 4><<<dim3(V / 32, B / 128, 1), dim3(256), 0, stream>>>(
        hn_b16, hn_b16, out_w, out_w, out_b, out_b,
        logp, logp, nullptr, partial, V);

    // 7. lse[b] = log(sum partial[b, :])
    lse_kernel<<<dim3(B), dim3(256), 0, stream>>>(partial, lse);

    // 8. logp -= lse[row]  (in place)
    sub_kernel<<<dim3(2000), dim3(256), 0, stream>>>((float4*)logp, lse);
}